// Round 7
// baseline (51.962 us; speedup 1.0000x reference)
//
#include <hip/hip_runtime.h>

#define LN_EPS 1e-5f

// ---------------------------------------------------------------------------
// Index algebra (verified passing rounds 2-6):
//   F[which][b][g][cc][cs*64+d] = P_{which}[b, s_i, h_i*64+d] + bias
//     s_i = (cc<2 ? 240+8*cc : 8*(cc-2)) + cs,  h_i = g*2 + (cc>>1)
//   Dt[b][gq][gk][cc][cs] = dot64(Fq, Fk) / 8
//   SFK[b][c][d] = 32 * sum_gv FK[b][gv][c>>3][(c&7)*64+d]   (pre-scaled)
//   attn: per (q,k) softmax over 32 c of (vq&vk ? Dt : 0); masked -> 1/32.
//   A[c] = sum_k attn;  ctx[b,q,h*64+d] = sum_c A[c]*SFK[b][c][d].
//   attn_out == 1.0 everywhere.
// Perf ledger: r2/r5 serial-K on read-only inputs is fine IF >=8 waves/CU;
// the persistent ~30us was the Wo stage reading MULTI-MB SCRATCH freshly
// written by the previous kernel (dirty cross-XCD L2 lines). This version
// hands off only A (512KB) + SFK/Dt (20KB) between kernels; ctx/Wpart gone.
// Scratch: F 32768 | Dt 1024 | SFK 4096 | A 131072  = 168,960 floats.
// ---------------------------------------------------------------------------

__device__ __forceinline__ bool sniff_mask_bytes(const unsigned int* m) {
    unsigned int acc = 0;
#pragma unroll
    for (int i = 0; i < 16; ++i) acc |= m[i];
    return acc > 1u;
}

// kP: projections -> F.  64 blocks x 512 thr (r5 version, measured fast).
__global__ __launch_bounds__(512) void kP_proj(
    const float* __restrict__ Qin, const float* __restrict__ Kin,
    const float* __restrict__ WQ, const float* __restrict__ bQ,
    const float* __restrict__ WK, const float* __restrict__ bK,
    float* __restrict__ F)
{
    int bx = blockIdx.x;
    int h_i = bx & 7, b = (bx >> 3) & 1, which = bx >> 4;
    int g = h_i >> 1, cc2 = (h_i & 1) * 2;
    int t = threadIdx.x;

    const float* In   = which ? Kin : Qin;
    const float* W    = which ? WK  : WQ;
    const float* bias = which ? bK  : bQ;

    __shared__ float Xl[16][512];
    int sb0 = (h_i & 1) ? 0 : 240;
#pragma unroll
    for (int i = 0; i < 4; ++i) {
        int idx = (i * 512 + t);
        int rl = idx >> 7, m4 = idx & 127;
        int srow = sb0 + (rl >> 3) * 8 + (rl & 7);
        ((float4*)&Xl[rl][0])[m4] =
            ((const float4*)&In[(b * 256 + srow) * 512])[m4];
    }
    __syncthreads();

    int d = t & 63, rr = t >> 6;
    int n = h_i * 64 + d;
    float acc0 = 0.f, acc1 = 0.f;
    const float* wp = W + n;
#pragma unroll 8
    for (int m = 0; m < 512; ++m) {
        float w = wp[m * 512];
        acc0 += Xl[rr][m] * w;
        acc1 += Xl[rr + 8][m] * w;
    }
    float bb = bias[n];
    int base = ((which * 2 + b) * 4 + g) * 4;
    F[(base + cc2)     * 512 + rr * 64 + d] = acc0 + bb;
    F[(base + cc2 + 1) * 512 + rr * 64 + d] = acc1 + bb;
}

// kC: Dt (8-lane dots + shfl) and SFK (pre-scaled x32).  48 blocks x 256 thr.
__global__ void kC_dtab_sfk(const float* __restrict__ F, float* __restrict__ Dt,
                            float* __restrict__ SFK) {
    int slot = blockIdx.x * 256 + threadIdx.x;
    if (slot < 8192) {
        int part = slot & 7, e = slot >> 3;
        int cs = e & 7, cc = (e >> 3) & 3, gk = (e >> 5) & 3,
            gq = (e >> 7) & 3, b = (e >> 9) & 1;
        const float* fq = F + ((b * 4 + gq) * 4 + cc) * 512 + cs * 64 + part * 8;
        const float* fk = F + (((2 + b) * 4 + gk) * 4 + cc) * 512 + cs * 64 + part * 8;
        float a = 0.f;
#pragma unroll
        for (int u = 0; u < 8; ++u) a += fq[u] * fk[u];
        a += __shfl_xor(a, 1);
        a += __shfl_xor(a, 2);
        a += __shfl_xor(a, 4);
        if (part == 0) Dt[e] = a * 0.125f;
    } else {
        int e = slot - 8192;
        int d = e & 63, c = (e >> 6) & 31, b = e >> 11;
        float a = 0.f;
#pragma unroll
        for (int gv = 0; gv < 4; ++gv)
            a += F[(((2 + b) * 4 + gv) * 4 + (c >> 3)) * 512 + (c & 7) * 64 + d];
        SFK[e] = 32.f * a;
    }
}

// kAttn2: 1024 blocks x 256 thr.  Wave per (h,q); 2 lanes per k, 16 c each.
// Output: only the A table, A[b][q][h][c] (c=0..31).  Optionally fills attnp.
__global__ void kAttn2(const float* __restrict__ Dt, const void* __restrict__ maskp,
                       float* __restrict__ Aout, float* __restrict__ attnp, int fill) {
    int vb = blockIdx.x, t = threadIdx.x;
    if (fill) ((float4*)attnp)[vb * 256 + t] = make_float4(1.f, 1.f, 1.f, 1.f);
    int qb = vb & 63, h = (vb >> 6) & 7, b = vb >> 9;
    int wave = t >> 6, l = t & 63;
    int q = qb * 4 + wave;
    int half = l & 1, klo = l >> 1;
    int g_q = q & 3;
    int i_q = h * 32 + (q >> 3);
    bool up_q = (q & 4) == 0;
    int ak = klo & 3;
    bool up_k = (klo & 4) == 0;

    bool mbytes = sniff_mask_bytes((const unsigned int*)maskp);

    float sq[16];
    const float* Db = Dt + ((b * 4 + g_q) * 4 + ak) * 32 + half * 16;
#pragma unroll
    for (int j = 0; j < 16; ++j) {
        int cc = half * 2 + (j >> 3);
        int row = g_q * 64 + 30 + cc;
        bool vq = up_q ? (i_q >= 256 - row) : (i_q <= 255 - row);
        sq[j] = vq ? Db[j] : 0.f;
    }

    float A[16];
#pragma unroll
    for (int j = 0; j < 16; ++j) A[j] = 0.f;

    int qrow = (b * 256 + q) * 256;
    for (int r = 0; r < 8; ++r) {
        int k = r * 32 + klo;
        bool masked = mbytes ? (((const unsigned char*)maskp)[qrow + k] != 0)
                             : (((const int*)maskp)[qrow + k] != 0);
        if (masked) {
#pragma unroll
            for (int j = 0; j < 16; ++j) A[j] += 0.03125f;
            continue;
        }
        int i_k = h * 32 + (k >> 3);
        float s[16];
        float mx = -1e30f;
#pragma unroll
        for (int j = 0; j < 16; ++j) {
            int cc = half * 2 + (j >> 3);
            int row = ak * 64 + 30 + cc;
            bool vk = up_k ? (i_k >= 256 - row) : (i_k <= 255 - row);
            s[j] = vk ? sq[j] : 0.f;
            mx = fmaxf(mx, s[j]);
        }
        mx = fmaxf(mx, __shfl_xor(mx, 1));
        float den = 0.f;
#pragma unroll
        for (int j = 0; j < 16; ++j) { s[j] = __expf(s[j] - mx); den += s[j]; }
        den += __shfl_xor(den, 1);
        float inv = 1.f / den;
#pragma unroll
        for (int j = 0; j < 16; ++j) A[j] += s[j] * inv;
    }

#pragma unroll
    for (int off = 2; off < 64; off <<= 1) {
#pragma unroll
        for (int j = 0; j < 16; ++j) A[j] += __shfl_xor(A[j], off);
    }

    // lane 0 holds c=0..15, lane 1 holds c=16..31
    if (l < 2) {
        float* Ap = Aout + ((b * 256 + q) * 8 + h) * 32 + l * 16;
#pragma unroll
        for (int j = 0; j < 16; ++j) Ap[j] = A[j];
    }
}

// kGLN: per 4-row block: reconstruct ctx rows from A+SFK in LDS, then
// full-K Wo GEMM (read-only Wo, streaming) + bias + residual + LayerNorm.
// 128 blocks x 512 thr.
__global__ __launch_bounds__(512) void kGLN(
    const float* __restrict__ A, const float* __restrict__ SFK,
    const float* __restrict__ Wo, const float* __restrict__ bo,
    const float* __restrict__ Qin, const float* __restrict__ gamma,
    const float* __restrict__ beta, float* __restrict__ out)
{
    __shared__ float Al[4][8][32];        // A rows     (4 KB)
    __shared__ float Sl[32][64];          // SFK[b]     (8 KB)
    __shared__ float ctx_lt[512 * 5];     // [m][r] pad5 (10 KB), bank-clean
    __shared__ float red[8][4][2];
    __shared__ float mrs[4][2];

    int blk = blockIdx.x, t = threadIdx.x;
    int r0 = blk * 4, b = r0 >> 8;

    if (t < 256) ((float4*)Al)[t] = ((const float4*)(A + r0 * 256))[t];
    ((float4*)Sl)[t] = ((const float4*)(SFK + b * 2048))[t];
    __syncthreads();

    // ctx value for output row r, ctx-col t:  sum_c Al[r][h][c] * Sl[c][d]
    {
        int h = t >> 6, d = t & 63;
        float c0 = 0.f, c1 = 0.f, c2 = 0.f, c3 = 0.f;
#pragma unroll
        for (int c = 0; c < 32; ++c) {
            float sf = Sl[c][d];
            c0 += Al[0][h][c] * sf;
            c1 += Al[1][h][c] * sf;
            c2 += Al[2][h][c] * sf;
            c3 += Al[3][h][c] * sf;
        }
        ctx_lt[t * 5 + 0] = c0;
        ctx_lt[t * 5 + 1] = c1;
        ctx_lt[t * 5 + 2] = c2;
        ctx_lt[t * 5 + 3] = c3;
    }
    __syncthreads();

    // y[r] = ctx_row_r . Wo[:,t] + bo[t] + Qin
    float a0 = 0.f, a1 = 0.f, a2 = 0.f, a3 = 0.f;
    const float* wp = Wo + t;
#pragma unroll 8
    for (int m = 0; m < 512; ++m) {
        float w = wp[m * 512];
        const float* cl = &ctx_lt[m * 5];
        a0 += cl[0] * w;
        a1 += cl[1] * w;
        a2 += cl[2] * w;
        a3 += cl[3] * w;
    }
    float bb = bo[t];
    float y[4];
    y[0] = a0 + bb + Qin[(r0 + 0) * 512 + t];
    y[1] = a1 + bb + Qin[(r0 + 1) * 512 + t];
    y[2] = a2 + bb + Qin[(r0 + 2) * 512 + t];
    y[3] = a3 + bb + Qin[(r0 + 3) * 512 + t];

    // row-wise LayerNorm over 512 cols (8 waves)
    float sy[4], sy2[4];
#pragma unroll
    for (int r = 0; r < 4; ++r) { sy[r] = y[r]; sy2[r] = y[r] * y[r]; }
#pragma unroll
    for (int off = 1; off < 64; off <<= 1) {
#pragma unroll
        for (int r = 0; r < 4; ++r) {
            sy[r]  += __shfl_xor(sy[r],  off);
            sy2[r] += __shfl_xor(sy2[r], off);
        }
    }
    int wv = t >> 6, l = t & 63;
    if (l == 0) {
#pragma unroll
        for (int r = 0; r < 4; ++r) { red[wv][r][0] = sy[r]; red[wv][r][1] = sy2[r]; }
    }
    __syncthreads();
    if (t < 4) {
        float s1 = 0.f, s2 = 0.f;
#pragma unroll
        for (int w = 0; w < 8; ++w) { s1 += red[w][t][0]; s2 += red[w][t][1]; }
        float mu  = s1 * (1.f / 512.f);
        float var = s2 * (1.f / 512.f) - mu * mu;
        mrs[t][0] = mu;
        mrs[t][1] = rsqrtf(var + LN_EPS);
    }
    __syncthreads();
    float gm = gamma[t], bt = beta[t];
#pragma unroll
    for (int r = 0; r < 4; ++r) {
        out[(r0 + r) * 512 + t] = (y[r] - mrs[r][0]) * mrs[r][1] * gm + bt;
    }
}

// plan-B only: restore attn_out region (which hosted scratch) to 1.0
__global__ void k5_fill(float* __restrict__ p, int n) {
    int i = (blockIdx.x * 256 + threadIdx.x) * 4;
    float4 one = make_float4(1.f, 1.f, 1.f, 1.f);
    for (; i < n; i += gridDim.x * 256 * 4) *(float4*)(p + i) = one;
}

extern "C" void kernel_launch(void* const* d_in, const int* in_sizes, int n_in,
                              void* d_out, int out_size, void* d_ws, size_t ws_size,
                              hipStream_t stream) {
    (void)in_sizes; (void)n_in; (void)out_size;
    const float* Qin  = (const float*)d_in[0];
    const float* Kin  = (const float*)d_in[1];
    const void*  mask = d_in[3];
    const float* WQ   = (const float*)d_in[4];
    const float* bQ   = (const float*)d_in[5];
    const float* WK   = (const float*)d_in[6];
    const float* bK   = (const float*)d_in[7];
    const float* Wo   = (const float*)d_in[10];
    const float* bo   = (const float*)d_in[11];
    const float* gamma= (const float*)d_in[12];
    const float* beta = (const float*)d_in[13];

    float* out   = (float*)d_out;
    float* attnp = out + 262144;                  // 1,048,576 floats (output 1)

    const size_t NEED = 168960ull * sizeof(float);
    int fill;
    float* scr;
    if (ws_size >= NEED) { scr = (float*)d_ws; fill = 1; }   // plan A
    else                 { scr = attnp;        fill = 0; }   // plan B

    float* F   = scr;                             // 32768
    float* Dt  = scr + 32768;                     // 1024
    float* SFK = scr + 33792;                     // 4096 (pre-scaled x32)
    float* A   = scr + 37888;                     // 131072

    kP_proj    <<<dim3(64),   dim3(512), 0, stream>>>(Qin, Kin, WQ, bQ, WK, bK, F);
    kC_dtab_sfk<<<dim3(48),   dim3(256), 0, stream>>>(F, Dt, SFK);
    kAttn2     <<<dim3(1024), dim3(256), 0, stream>>>(Dt, mask, A, attnp, fill);
    kGLN       <<<dim3(128),  dim3(512), 0, stream>>>(A, SFK, Wo, bo, Qin, gamma, beta, out);
    if (!fill) k5_fill<<<dim3(256), dim3(256), 0, stream>>>(attnp, 1048576);
}